// Round 1
// baseline (606.928 us; speedup 1.0000x reference)
//
#include <hip/hip_runtime.h>
#include <math.h>

#define C      256
#define NPIX   196
#define BATCH  64
#define MAT    (C*C)                 // 65536
#define OUTPB  ((C*(C+1))/2)         // 32896

// ---------------------------------------------------------------------------
// rowsum: s[b*C + c] = sum_m x[b,c,m]   (one wave per row)
// ---------------------------------------------------------------------------
__global__ __launch_bounds__(256) void rowsum_k(const float* __restrict__ x,
                                                float* __restrict__ s) {
    int wave = threadIdx.x >> 6;
    int lane = threadIdx.x & 63;
    int row  = blockIdx.x * 4 + wave;          // [0, BATCH*C)
    const float* xr = x + (size_t)row * NPIX;
    float v = 0.f;
    for (int m = lane; m < NPIX; m += 64) v += xr[m];
    #pragma unroll
    for (int off = 32; off; off >>= 1) v += __shfl_down(v, off, 64);
    if (lane == 0) s[row] = v;
}

// ---------------------------------------------------------------------------
// Gram + centering: S[b,c,d] = (1/n) sum_m x[c,m]x[d,m] - (1/n^2) s_c s_d
// tile 128x128, K = 196 padded to 208, BK=16
// ---------------------------------------------------------------------------
__global__ __launch_bounds__(256) void gram_k(const float* __restrict__ x,
                                              const float* __restrict__ s,
                                              float* __restrict__ S) {
    __shared__ float As[16][132];
    __shared__ float Bs[16][132];
    const int b  = blockIdx.z;
    const int bm = blockIdx.y, bn = blockIdx.x;
    const float* xb = x + (size_t)b * (C * NPIX);
    const int t  = threadIdx.x;
    const int tm = t & 15, tn = t >> 4;

    float acc[8][8];
    #pragma unroll
    for (int i = 0; i < 8; ++i)
        #pragma unroll
        for (int j = 0; j < 8; ++j) acc[i][j] = 0.f;

    const int lrow = t >> 2;          // 0..63
    const int lk4  = (t & 3) * 4;     // 0,4,8,12

    for (int k0 = 0; k0 < 208; k0 += 16) {
        #pragma unroll
        for (int p = 0; p < 2; ++p) {
            int row = lrow + p * 64;
            int kk  = k0 + lk4;
            float4 v = make_float4(0.f, 0.f, 0.f, 0.f);
            float4 w = make_float4(0.f, 0.f, 0.f, 0.f);
            if (kk < NPIX) {
                v = *(const float4*)(xb + (size_t)(bm * 128 + row) * NPIX + kk);
                w = *(const float4*)(xb + (size_t)(bn * 128 + row) * NPIX + kk);
            }
            As[lk4 + 0][row] = v.x; As[lk4 + 1][row] = v.y;
            As[lk4 + 2][row] = v.z; As[lk4 + 3][row] = v.w;
            Bs[lk4 + 0][row] = w.x; Bs[lk4 + 1][row] = w.y;
            Bs[lk4 + 2][row] = w.z; Bs[lk4 + 3][row] = w.w;
        }
        __syncthreads();
        #pragma unroll
        for (int k = 0; k < 16; ++k) {
            float av[8], bv[8];
            *(float4*)(av)     = *(const float4*)(&As[k][tm * 8]);
            *(float4*)(av + 4) = *(const float4*)(&As[k][tm * 8 + 4]);
            *(float4*)(bv)     = *(const float4*)(&Bs[k][tn * 8]);
            *(float4*)(bv + 4) = *(const float4*)(&Bs[k][tn * 8 + 4]);
            #pragma unroll
            for (int i = 0; i < 8; ++i)
                #pragma unroll
                for (int j = 0; j < 8; ++j)
                    acc[i][j] = fmaf(av[i], bv[j], acc[i][j]);
        }
        __syncthreads();
    }

    const float invn  = 1.0f / NPIX;
    const float invn2 = invn * invn;
    const float* sb = s + b * C;
    const int grow0 = bm * 128 + tm * 8;
    const int gcol0 = bn * 128 + tn * 8;
    float sA[8], sB[8];
    #pragma unroll
    for (int i = 0; i < 8; ++i) { sA[i] = sb[grow0 + i]; sB[i] = sb[gcol0 + i]; }
    float* ob = S + (size_t)b * MAT;
    #pragma unroll
    for (int i = 0; i < 8; ++i) {
        #pragma unroll
        for (int j = 0; j < 8; ++j) {
            float val = acc[i][j] * invn - sA[i] * sB[j] * invn2;
            ob[(size_t)(grow0 + i) * C + gcol0 + j] = val;
        }
    }
}

// ---------------------------------------------------------------------------
// trace: tr[b] = sum_c S[b,c,c]
// ---------------------------------------------------------------------------
__global__ __launch_bounds__(256) void trace_k(const float* __restrict__ S,
                                               float* __restrict__ tr) {
    int b = blockIdx.x;
    int c = threadIdx.x;
    float v = S[(size_t)b * MAT + (size_t)c * C + c];
    __shared__ float red[4];
    #pragma unroll
    for (int off = 32; off; off >>= 1) v += __shfl_down(v, off, 64);
    int lane = c & 63, w = c >> 6;
    if (lane == 0) red[w] = v;
    __syncthreads();
    if (c == 0) tr[b] = red[0] + red[1] + red[2] + red[3];
}

// ---------------------------------------------------------------------------
// prep: A = S / tr (in place over S), B = 1.5 I - 0.5 A
// ---------------------------------------------------------------------------
__global__ __launch_bounds__(256) void prep_k(float* __restrict__ S,
                                              float* __restrict__ Bm,
                                              const float* __restrict__ tr) {
    int b = blockIdx.y;
    size_t base = (size_t)b * MAT;
    float inv = 1.0f / tr[b];
    int i = (blockIdx.x * 256 + threadIdx.x) * 4;
    float4 v = *(const float4*)(S + base + i);
    int row = i >> 8, col0 = i & 255;
    float a[4] = { v.x * inv, v.y * inv, v.z * inv, v.w * inv };
    float bb[4];
    #pragma unroll
    for (int j = 0; j < 4; ++j)
        bb[j] = ((col0 + j) == row ? 1.5f : 0.0f) - 0.5f * a[j];
    *(float4*)(S + base + i)  = make_float4(a[0], a[1], a[2], a[3]);
    *(float4*)(Bm + base + i) = make_float4(bb[0], bb[1], bb[2], bb[3]);
}

// ---------------------------------------------------------------------------
// batched 256x256x256 fp32 matmul, tile 128x128, BK=16, 8x8 per thread.
// MODE 0: out = P          MODE 1: out = 1.5I - 0.5P
// MODE 2: out = triu_packed(P * sqrt(tr[b]))
// ---------------------------------------------------------------------------
template <int MODE>
__global__ __launch_bounds__(256) void mm_k(const float* __restrict__ A,
                                            const float* __restrict__ Bm,
                                            float* __restrict__ out,
                                            const float* __restrict__ tr) {
    const int bm = blockIdx.y, bn = blockIdx.x;
    if (MODE == 2 && bm > bn) return;   // strictly-lower tile: nothing to write
    __shared__ float As[16][132];
    __shared__ float Bs[16][132];
    const int b = blockIdx.z;
    const size_t mb = (size_t)b * MAT;
    const float* Ab = A + mb;
    const float* Bb = Bm + mb;
    const int t  = threadIdx.x;
    const int tm = t & 15, tn = t >> 4;

    float acc[8][8];
    #pragma unroll
    for (int i = 0; i < 8; ++i)
        #pragma unroll
        for (int j = 0; j < 8; ++j) acc[i][j] = 0.f;

    const int lrowA  = t >> 2;         // 0..63
    const int lk4A   = (t & 3) * 4;    // 0,4,8,12
    const int lcol4B = (t & 31) * 4;   // 0..124
    const int lkB    = t >> 5;         // 0..7

    for (int k0 = 0; k0 < C; k0 += 16) {
        #pragma unroll
        for (int p = 0; p < 2; ++p) {
            int row = lrowA + p * 64;
            float4 v = *(const float4*)(Ab + (size_t)(bm * 128 + row) * C + k0 + lk4A);
            As[lk4A + 0][row] = v.x; As[lk4A + 1][row] = v.y;
            As[lk4A + 2][row] = v.z; As[lk4A + 3][row] = v.w;
            int k = lkB + p * 8;
            float4 w = *(const float4*)(Bb + (size_t)(k0 + k) * C + bn * 128 + lcol4B);
            *(float4*)&Bs[k][lcol4B] = w;
        }
        __syncthreads();
        #pragma unroll
        for (int k = 0; k < 16; ++k) {
            float av[8], bv[8];
            *(float4*)(av)     = *(const float4*)(&As[k][tm * 8]);
            *(float4*)(av + 4) = *(const float4*)(&As[k][tm * 8 + 4]);
            *(float4*)(bv)     = *(const float4*)(&Bs[k][tn * 8]);
            *(float4*)(bv + 4) = *(const float4*)(&Bs[k][tn * 8 + 4]);
            #pragma unroll
            for (int i = 0; i < 8; ++i)
                #pragma unroll
                for (int j = 0; j < 8; ++j)
                    acc[i][j] = fmaf(av[i], bv[j], acc[i][j]);
        }
        __syncthreads();
    }

    const int grow0 = bm * 128 + tm * 8;
    const int gcol0 = bn * 128 + tn * 8;

    if (MODE == 0) {
        float* ob = out + mb;
        #pragma unroll
        for (int i = 0; i < 8; ++i) {
            *(float4*)(ob + (size_t)(grow0 + i) * C + gcol0) =
                make_float4(acc[i][0], acc[i][1], acc[i][2], acc[i][3]);
            *(float4*)(ob + (size_t)(grow0 + i) * C + gcol0 + 4) =
                make_float4(acc[i][4], acc[i][5], acc[i][6], acc[i][7]);
        }
    } else if (MODE == 1) {
        float* ob = out + mb;
        #pragma unroll
        for (int i = 0; i < 8; ++i) {
            int r = grow0 + i;
            float v[8];
            #pragma unroll
            for (int j = 0; j < 8; ++j)
                v[j] = ((gcol0 + j) == r ? 1.5f : 0.0f) - 0.5f * acc[i][j];
            *(float4*)(ob + (size_t)r * C + gcol0)     = make_float4(v[0], v[1], v[2], v[3]);
            *(float4*)(ob + (size_t)r * C + gcol0 + 4) = make_float4(v[4], v[5], v[6], v[7]);
        }
    } else {
        float scale = sqrtf(tr[b]);
        float* ob = out + (size_t)b * OUTPB;
        #pragma unroll
        for (int i = 0; i < 8; ++i) {
            int r = grow0 + i;
            int rowoff = r * C - (r * (r - 1)) / 2 - r;   // + c0 gives packed idx
            #pragma unroll
            for (int j = 0; j < 8; ++j) {
                int c0 = gcol0 + j;
                if (c0 >= r) ob[rowoff + c0] = acc[i][j] * scale;
            }
        }
    }
}

// ---------------------------------------------------------------------------
extern "C" void kernel_launch(void* const* d_in, const int* in_sizes, int n_in,
                              void* d_out, int out_size, void* d_ws, size_t ws_size,
                              hipStream_t stream) {
    const float* x = (const float*)d_in[0];
    float* out = (float*)d_out;
    float* ws  = (float*)d_ws;

    float* buf[5];
    for (int i = 0; i < 5; ++i) buf[i] = ws + (size_t)i * MAT * BATCH;
    float* s  = ws + (size_t)5 * MAT * BATCH;   // BATCH*C floats
    float* tr = s + BATCH * C;                  // BATCH floats

    dim3 blk(256);
    dim3 gMM(2, 2, BATCH);

    // 1. row sums
    rowsum_k<<<dim3(BATCH * C / 4), blk, 0, stream>>>(x, s);
    // 2. covariance -> buf0 (S)
    gram_k<<<gMM, blk, 0, stream>>>(x, s, buf[0]);
    // 3. trace
    trace_k<<<dim3(BATCH), blk, 0, stream>>>(buf[0], tr);
    // 4. A = S/tr (in-place buf0), B1 = 1.5I - 0.5A -> buf1 ; Z = buf1
    prep_k<<<dim3(64, BATCH), blk, 0, stream>>>(buf[0], buf[1], tr);
    // 5. Y1 = A @ B1 -> buf2
    mm_k<0><<<gMM, blk, 0, stream>>>(buf[0], buf[1], buf[2], nullptr);

    // iter 0:  Z=buf1 Y=buf2 -> Bn=buf3, Ynew=buf4, Znew=buf0
    mm_k<1><<<gMM, blk, 0, stream>>>(buf[1], buf[2], buf[3], nullptr);
    mm_k<0><<<gMM, blk, 0, stream>>>(buf[2], buf[3], buf[4], nullptr);
    mm_k<0><<<gMM, blk, 0, stream>>>(buf[3], buf[1], buf[0], nullptr);
    // iter 1:  Z=buf0 Y=buf4 -> Bn=buf3, Ynew=buf2, Znew=buf1
    mm_k<1><<<gMM, blk, 0, stream>>>(buf[0], buf[4], buf[3], nullptr);
    mm_k<0><<<gMM, blk, 0, stream>>>(buf[4], buf[3], buf[2], nullptr);
    mm_k<0><<<gMM, blk, 0, stream>>>(buf[3], buf[0], buf[1], nullptr);
    // iter 2:  Z=buf1 Y=buf2 -> Bn=buf3, Ynew=buf4, Znew=buf0
    mm_k<1><<<gMM, blk, 0, stream>>>(buf[1], buf[2], buf[3], nullptr);
    mm_k<0><<<gMM, blk, 0, stream>>>(buf[2], buf[3], buf[4], nullptr);
    mm_k<0><<<gMM, blk, 0, stream>>>(buf[3], buf[1], buf[0], nullptr);
    // final:   Z=buf0 Y=buf4
    mm_k<1><<<gMM, blk, 0, stream>>>(buf[0], buf[4], buf[3], nullptr);
    mm_k<2><<<gMM, blk, 0, stream>>>(buf[4], buf[3], out, tr);
}

// Round 2
// 439.850 us; speedup vs baseline: 1.3799x; 1.3799x over previous
//
#include <hip/hip_runtime.h>
#include <math.h>

#define C      256
#define NPIX   196
#define BATCH  64
#define MAT    65536                  // C*C
#define PL     4194304                // BATCH*MAT  (one bf16 plane, in elements)
#define OUTPB  32896                  // C*(C+1)/2

typedef short s16x8 __attribute__((ext_vector_type(8)));
typedef float f32x4 __attribute__((ext_vector_type(4)));

// ---- bf16 split helpers (RNE) ---------------------------------------------
__device__ __forceinline__ short bfhi(float v) {
    unsigned int u = __float_as_uint(v);
    u = (u + 0x7fffu + ((u >> 16) & 1u)) >> 16;
    return (short)u;
}
__device__ __forceinline__ float bff(short h) {
    return __uint_as_float(((unsigned int)(unsigned short)h) << 16);
}
__device__ __forceinline__ void bfsplit(float v, short& h, short& l) {
    h = bfhi(v);
    l = bfhi(v - bff(h));
}

// ---------------------------------------------------------------------------
__global__ void zero_k(float* __restrict__ t) { t[threadIdx.x] = 0.f; }

// ---------------------------------------------------------------------------
// Fused: row-mean centering, bf16 hi/lo split, zero-pad K 196->256,
// and per-batch sum(xc^2) (= n * trace(sigma)) via atomics.
// One wave per row; 4096 blocks x 256 threads.
// ---------------------------------------------------------------------------
__global__ __launch_bounds__(256) void convert_k(const float* __restrict__ x,
                                                 short* __restrict__ xc,
                                                 float* __restrict__ trsum) {
    const int wave = threadIdx.x >> 6, lane = threadIdx.x & 63;
    const int rowg = blockIdx.x * 4 + wave;          // [0, BATCH*C)
    const int b = rowg >> 8;
    const float* xr = x + (size_t)rowg * NPIX;
    float v[4];
    #pragma unroll
    for (int i = 0; i < 4; ++i) {
        int c = lane + (i << 6);
        v[i] = (c < NPIX) ? xr[c] : 0.f;
    }
    float s = v[0] + v[1] + v[2] + v[3];
    #pragma unroll
    for (int off = 32; off; off >>= 1) s += __shfl_xor(s, off, 64);
    const float mean = s * (1.f / NPIX);

    short* oh = xc + (size_t)b * MAT + (size_t)(rowg & 255) * C;
    short* ol = oh + PL;
    float sq = 0.f;
    #pragma unroll
    for (int i = 0; i < 4; ++i) {
        int c = lane + (i << 6);
        float w = (c < NPIX) ? (v[i] - mean) : 0.f;
        sq += w * w;
        short h, l;
        bfsplit(w, h, l);
        oh[c] = h;
        ol[c] = l;
    }
    #pragma unroll
    for (int off = 32; off; off >>= 1) sq += __shfl_xor(sq, off, 64);
    if (lane == 0) atomicAdd(trsum + b, sq);
}

// ---------------------------------------------------------------------------
// Batched 256x256x256 split-bf16 MFMA matmul, tile 128x128 per block,
// 4 waves each computing a 64x64 quadrant via 4x4 mfma_f32_16x16x32_bf16.
// Both operand fragments are loaded with IDENTICAL addressing from row-major
// matrices (valid because every matrix in the chain is symmetric).
// MODE 0: P -> hi/lo planes (o0)
// MODE 1: 1.5I - 0.5P -> planes (o0)
// MODE 2: triu-packed fp32 of P*sqrt(trsum/196) -> outf
// MODE 3: (gram) A = P/trsum -> o0 planes ; B1 = 1.5I - 0.5A -> o1 planes
// ---------------------------------------------------------------------------
template <int MODE>
__global__ __launch_bounds__(256) void mm_k(const short* __restrict__ A,
                                            const short* __restrict__ B,
                                            short* __restrict__ o0,
                                            short* __restrict__ o1,
                                            float* __restrict__ outf,
                                            const float* __restrict__ trsum) {
    const int bn = blockIdx.x, bm = blockIdx.y, b = blockIdx.z;
    if (MODE == 2 && bm > bn) return;

    __shared__ __align__(16) short lds[4 * 8192];   // planes: Ah, Al, Bh, Bl

    const int t = threadIdx.x;
    const int lane = t & 63, wid = t >> 6;
    const int wr = wid >> 1, wc = wid & 1;
    const int lr = lane & 15, lg = lane >> 4;

    const size_t mb = (size_t)b * MAT;
    const short* Ah = A + mb;
    const short* Al = A + (size_t)PL + mb;
    const short* Bh = B + mb;
    const short* Bl = B + (size_t)PL + mb;
    const int rowA0 = bm * 128, rowB0 = bn * 128;

    f32x4 acc[4][4];
    const f32x4 zero = {0.f, 0.f, 0.f, 0.f};
    #pragma unroll
    for (int i = 0; i < 4; ++i)
        #pragma unroll
        for (int j = 0; j < 4; ++j) acc[i][j] = zero;

    for (int k0 = 0; k0 < C; k0 += 64) {
        // stage 4 planes of [128 rows x 64 k] with XOR-(row&7) swizzle
        #pragma unroll
        for (int i = 0; i < 16; ++i) {
            int u = i * 256 + t;
            int p = u >> 10, row = (u >> 3) & 127, ch = u & 7;
            const short* src = (p == 0) ? Ah + (size_t)(rowA0 + row) * C
                             : (p == 1) ? Al + (size_t)(rowA0 + row) * C
                             : (p == 2) ? Bh + (size_t)(rowB0 + row) * C
                                        : Bl + (size_t)(rowB0 + row) * C;
            s16x8 v = *(const s16x8*)(src + k0 + ch * 8);
            *(s16x8*)&lds[(p << 13) + row * 64 + ((ch ^ (row & 7)) << 3)] = v;
        }
        __syncthreads();
        #pragma unroll
        for (int kk = 0; kk < 64; kk += 32) {
            s16x8 ah[4], al[4], bh[4], bl[4];
            #pragma unroll
            for (int fb = 0; fb < 4; ++fb) {
                int ra = wr * 64 + fb * 16 + lr;
                int ca = ((kk >> 3) + lg) ^ (ra & 7);
                ah[fb] = *(const s16x8*)&lds[0 * 8192 + ra * 64 + (ca << 3)];
                al[fb] = *(const s16x8*)&lds[1 * 8192 + ra * 64 + (ca << 3)];
                int rb = wc * 64 + fb * 16 + lr;
                int cb = ((kk >> 3) + lg) ^ (rb & 7);
                bh[fb] = *(const s16x8*)&lds[2 * 8192 + rb * 64 + (cb << 3)];
                bl[fb] = *(const s16x8*)&lds[3 * 8192 + rb * 64 + (cb << 3)];
            }
            #pragma unroll
            for (int i = 0; i < 4; ++i)
                #pragma unroll
                for (int j = 0; j < 4; ++j) {
                    acc[i][j] = __builtin_amdgcn_mfma_f32_16x16x32_bf16(ah[i], bh[j], acc[i][j], 0, 0, 0);
                    acc[i][j] = __builtin_amdgcn_mfma_f32_16x16x32_bf16(ah[i], bl[j], acc[i][j], 0, 0, 0);
                    acc[i][j] = __builtin_amdgcn_mfma_f32_16x16x32_bf16(al[i], bh[j], acc[i][j], 0, 0, 0);
                }
        }
        __syncthreads();
    }

    // ---- epilogue ----
    float ts = 0.f;
    if (MODE == 2 || MODE == 3) ts = trsum[b];
    const float invT  = (MODE == 3) ? (1.f / ts) : 0.f;
    const float scale = (MODE == 2) ? sqrtf(ts * (1.f / NPIX)) : 0.f;

    #pragma unroll
    for (int i = 0; i < 4; ++i) {
        #pragma unroll
        for (int j = 0; j < 4; ++j) {
            #pragma unroll
            for (int q = 0; q < 4; ++q) {
                const int r_t = bm * 128 + wr * 64 + i * 16 + lg * 4 + q;
                const int c_t = bn * 128 + wc * 64 + j * 16 + lr;
                const float v = acc[i][j][q];
                if (MODE == 0) {
                    short h, l;
                    bfsplit(v, h, l);
                    o0[mb + (size_t)r_t * C + c_t] = h;
                    o0[(size_t)PL + mb + (size_t)r_t * C + c_t] = l;
                } else if (MODE == 1) {
                    float w = ((r_t == c_t) ? 1.5f : 0.f) - 0.5f * v;
                    short h, l;
                    bfsplit(w, h, l);
                    o0[mb + (size_t)r_t * C + c_t] = h;
                    o0[(size_t)PL + mb + (size_t)r_t * C + c_t] = l;
                } else if (MODE == 3) {
                    float a = v * invT;
                    short h, l;
                    bfsplit(a, h, l);
                    o0[mb + (size_t)r_t * C + c_t] = h;
                    o0[(size_t)PL + mb + (size_t)r_t * C + c_t] = l;
                    float w = ((r_t == c_t) ? 1.5f : 0.f) - 0.5f * a;
                    bfsplit(w, h, l);
                    o1[mb + (size_t)r_t * C + c_t] = h;
                    o1[(size_t)PL + mb + (size_t)r_t * C + c_t] = l;
                } else {
                    if (c_t >= r_t) {
                        int off = r_t * C - (r_t * (r_t - 1)) / 2 - r_t + c_t;
                        outf[(size_t)b * OUTPB + off] = v * scale;
                    }
                }
            }
        }
    }
}

// ---------------------------------------------------------------------------
extern "C" void kernel_launch(void* const* d_in, const int* in_sizes, int n_in,
                              void* d_out, int out_size, void* d_ws, size_t ws_size,
                              hipStream_t stream) {
    const float* x = (const float*)d_in[0];
    float* out = (float*)d_out;
    short* base = (short*)d_ws;
    short* buf0 = base;
    short* buf1 = base + (size_t)2 * PL;
    short* buf2 = base + (size_t)4 * PL;
    short* buf3 = base + (size_t)6 * PL;
    float* trsum = (float*)(base + (size_t)8 * PL);

    dim3 blk(256);
    dim3 g(2, 2, BATCH);

    zero_k<<<1, 64, 0, stream>>>(trsum);
    // xc (centered, split, padded) -> buf2 ; trsum[b] = sum(xc^2)
    convert_k<<<dim3(BATCH * C / 4), blk, 0, stream>>>(x, buf2, trsum);
    // Gram + prep: A -> buf0, B1 -> buf1
    mm_k<3><<<g, blk, 0, stream>>>(buf2, buf2, buf0, buf1, nullptr, trsum);
    // Y1 = A @ B1 -> buf2 ; Z = B1 (buf1)
    mm_k<0><<<g, blk, 0, stream>>>(buf0, buf1, buf2, nullptr, nullptr, nullptr);
    // iter 1: Z=1 Y=2 -> Bn=3, Ynew=0, Znew=2
    mm_k<1><<<g, blk, 0, stream>>>(buf1, buf2, buf3, nullptr, nullptr, nullptr);
    mm_k<0><<<g, blk, 0, stream>>>(buf2, buf3, buf0, nullptr, nullptr, nullptr);
    mm_k<0><<<g, blk, 0, stream>>>(buf3, buf1, buf2, nullptr, nullptr, nullptr);
    // iter 2: Z=2 Y=0 -> Bn=1, Ynew=3, Znew=0
    mm_k<1><<<g, blk, 0, stream>>>(buf2, buf0, buf1, nullptr, nullptr, nullptr);
    mm_k<0><<<g, blk, 0, stream>>>(buf0, buf1, buf3, nullptr, nullptr, nullptr);
    mm_k<0><<<g, blk, 0, stream>>>(buf1, buf2, buf0, nullptr, nullptr, nullptr);
    // iter 3: Z=0 Y=3 -> Bn=1, Ynew=2, Znew=3
    mm_k<1><<<g, blk, 0, stream>>>(buf0, buf3, buf1, nullptr, nullptr, nullptr);
    mm_k<0><<<g, blk, 0, stream>>>(buf3, buf1, buf2, nullptr, nullptr, nullptr);
    mm_k<0><<<g, blk, 0, stream>>>(buf1, buf0, buf3, nullptr, nullptr, nullptr);
    // final: Z=3 Y=2 -> Bf=0 ; out = triu(Y @ Bf * sqrt(tr))
    mm_k<1><<<g, blk, 0, stream>>>(buf3, buf2, buf0, nullptr, nullptr, nullptr);
    mm_k<2><<<g, blk, 0, stream>>>(buf2, buf0, nullptr, nullptr, out, trsum);
}

// Round 3
// 312.757 us; speedup vs baseline: 1.9406x; 1.4064x over previous
//
#include <hip/hip_runtime.h>
#include <math.h>

#define C      256
#define NPIX   196
#define BATCH  64
#define MAT    65536                  // C*C
#define PL     4194304                // BATCH*MAT  (one bf16 plane, in elements)
#define OUTPB  32896                  // C*(C+1)/2

typedef short s16x8 __attribute__((ext_vector_type(8)));
typedef float f32x4 __attribute__((ext_vector_type(4)));

// ---- bf16 split helpers (RNE) ---------------------------------------------
__device__ __forceinline__ short bfhi(float v) {
    unsigned int u = __float_as_uint(v);
    u = (u + 0x7fffu + ((u >> 16) & 1u)) >> 16;
    return (short)u;
}
__device__ __forceinline__ float bff(short h) {
    return __uint_as_float(((unsigned int)(unsigned short)h) << 16);
}
__device__ __forceinline__ void bfsplit(float v, short& h, short& l) {
    h = bfhi(v);
    l = bfhi(v - bff(h));
}

// ---------------------------------------------------------------------------
// Fused: row-mean centering, bf16 hi/lo split, zero-pad K 196->256.
// Per-row sum(xc^2) -> rowsq (NO atomics — same-line atomic serialization
// across XCDs cost ~115 us in round 2).
// ---------------------------------------------------------------------------
__global__ __launch_bounds__(256) void convert_k(const float* __restrict__ x,
                                                 short* __restrict__ xc,
                                                 float* __restrict__ rowsq) {
    const int wave = threadIdx.x >> 6, lane = threadIdx.x & 63;
    const int rowg = blockIdx.x * 4 + wave;          // [0, BATCH*C)
    const int b = rowg >> 8;
    const float* xr = x + (size_t)rowg * NPIX;
    float v[4];
    #pragma unroll
    for (int i = 0; i < 4; ++i) {
        int c = lane + (i << 6);
        v[i] = (c < NPIX) ? xr[c] : 0.f;
    }
    float s = v[0] + v[1] + v[2] + v[3];
    #pragma unroll
    for (int off = 32; off; off >>= 1) s += __shfl_xor(s, off, 64);
    const float mean = s * (1.f / NPIX);

    short* oh = xc + (size_t)b * MAT + (size_t)(rowg & 255) * C;
    short* ol = oh + PL;
    float sq = 0.f;
    #pragma unroll
    for (int i = 0; i < 4; ++i) {
        int c = lane + (i << 6);
        float w = (c < NPIX) ? (v[i] - mean) : 0.f;
        sq += w * w;
        short h, l;
        bfsplit(w, h, l);
        oh[c] = h;
        ol[c] = l;
    }
    #pragma unroll
    for (int off = 32; off; off >>= 1) sq += __shfl_xor(sq, off, 64);
    if (lane == 0) rowsq[rowg] = sq;
}

// ---------------------------------------------------------------------------
// trsum[b] = sum_c rowsq[b*256+c]   (64 blocks x 256 threads)
// ---------------------------------------------------------------------------
__global__ __launch_bounds__(256) void tracered_k(const float* __restrict__ rowsq,
                                                  float* __restrict__ trsum) {
    const int b = blockIdx.x, t = threadIdx.x;
    float v = rowsq[b * 256 + t];
    __shared__ float red[4];
    #pragma unroll
    for (int off = 32; off; off >>= 1) v += __shfl_xor(v, off, 64);
    if ((t & 63) == 0) red[t >> 6] = v;
    __syncthreads();
    if (t == 0) trsum[b] = red[0] + red[1] + red[2] + red[3];
}

// ---------------------------------------------------------------------------
// Batched 256x256x256 split-bf16 MFMA matmul.
// Tile BM=64 x BN=128 per block -> grid (2,4,BATCH) = 512 blocks = 2/CU.
// 4 waves (2x2), wave tile 32x64 via 2x4 mfma_f32_16x16x32_bf16, 3-term split.
// Operands loaded with identical addressing (all matrices symmetric).
// MODE 0: P            MODE 1: 1.5I-0.5P       MODE 2: triu(P*sqrt(tr/n))
// MODE 3: A=P/trsum -> o0 ; 1.5I-0.5A -> o1
// ---------------------------------------------------------------------------
template <int MODE>
__global__ __launch_bounds__(256) void mm_k(const short* __restrict__ A,
                                            const short* __restrict__ B,
                                            short* __restrict__ o0,
                                            short* __restrict__ o1,
                                            float* __restrict__ outf,
                                            const float* __restrict__ trsum) {
    const int bn = blockIdx.x, bm = blockIdx.y, b = blockIdx.z;
    if (MODE == 2 && bn == 0 && bm >= 2) return;   // fully strictly-lower tile

    __shared__ __align__(16) short lds[24576];     // Ah,Al: 2x4096  Bh,Bl: 2x8192

    const int t = threadIdx.x;
    const int lane = t & 63, wid = t >> 6;
    const int wr = wid >> 1, wc = wid & 1;         // wave grid 2x2
    const int lr = lane & 15, lg = lane >> 4;

    const size_t mb = (size_t)b * MAT;
    const short* Ah = A + mb;
    const short* Bh = B + mb;
    const int rowA0 = bm * 64, rowB0 = bn * 128;

    f32x4 acc[2][4];
    const f32x4 zero = {0.f, 0.f, 0.f, 0.f};
    #pragma unroll
    for (int i = 0; i < 2; ++i)
        #pragma unroll
        for (int j = 0; j < 4; ++j) acc[i][j] = zero;

    for (int k0 = 0; k0 < C; k0 += 64) {
        // stage: A 1024 chunks (i=0..3), B 2048 chunks (i=4..11), 16B each
        #pragma unroll
        for (int i = 0; i < 12; ++i) {
            const int u = i * 256 + t;
            int plane, rr, ch, ldsbase;
            const short* src;
            if (i < 4) {
                plane = u >> 9; rr = (u >> 3) & 63; ch = u & 7;
                src = Ah + (size_t)plane * PL + (size_t)(rowA0 + rr) * C;
                ldsbase = plane * 4096;
            } else {
                const int v2 = u - 1024;
                plane = v2 >> 10; rr = (v2 >> 3) & 127; ch = v2 & 7;
                src = Bh + (size_t)plane * PL + (size_t)(rowB0 + rr) * C;
                ldsbase = 8192 + plane * 8192;
            }
            s16x8 v = *(const s16x8*)(src + k0 + ch * 8);
            *(s16x8*)&lds[ldsbase + rr * 64 + ((ch ^ (rr & 7)) << 3)] = v;
        }
        __syncthreads();
        #pragma unroll
        for (int kk = 0; kk < 64; kk += 32) {
            s16x8 ah[2], al[2], bh[4], bl[4];
            #pragma unroll
            for (int i = 0; i < 2; ++i) {
                const int ra = wr * 32 + i * 16 + lr;
                const int ca = ((kk >> 3) + lg) ^ (ra & 7);
                ah[i] = *(const s16x8*)&lds[ra * 64 + (ca << 3)];
                al[i] = *(const s16x8*)&lds[4096 + ra * 64 + (ca << 3)];
            }
            #pragma unroll
            for (int j = 0; j < 4; ++j) {
                const int rb = wc * 64 + j * 16 + lr;
                const int cb = ((kk >> 3) + lg) ^ (rb & 7);
                bh[j] = *(const s16x8*)&lds[8192 + rb * 64 + (cb << 3)];
                bl[j] = *(const s16x8*)&lds[16384 + rb * 64 + (cb << 3)];
            }
            #pragma unroll
            for (int i = 0; i < 2; ++i)
                #pragma unroll
                for (int j = 0; j < 4; ++j) {
                    acc[i][j] = __builtin_amdgcn_mfma_f32_16x16x32_bf16(ah[i], bh[j], acc[i][j], 0, 0, 0);
                    acc[i][j] = __builtin_amdgcn_mfma_f32_16x16x32_bf16(ah[i], bl[j], acc[i][j], 0, 0, 0);
                    acc[i][j] = __builtin_amdgcn_mfma_f32_16x16x32_bf16(al[i], bh[j], acc[i][j], 0, 0, 0);
                }
        }
        __syncthreads();
    }

    // ---- epilogue ----
    float ts = 0.f;
    if (MODE == 2 || MODE == 3) ts = trsum[b];
    const float invT  = (MODE == 3) ? (1.f / ts) : 0.f;
    const float scale = (MODE == 2) ? sqrtf(ts * (1.f / NPIX)) : 0.f;

    #pragma unroll
    for (int i = 0; i < 2; ++i) {
        #pragma unroll
        for (int j = 0; j < 4; ++j) {
            #pragma unroll
            for (int q = 0; q < 4; ++q) {
                const int r_t = bm * 64 + wr * 32 + i * 16 + lg * 4 + q;
                const int c_t = bn * 128 + wc * 64 + j * 16 + lr;
                const float v = acc[i][j][q];
                if (MODE == 0) {
                    short h, l;
                    bfsplit(v, h, l);
                    o0[mb + (size_t)r_t * C + c_t] = h;
                    o0[(size_t)PL + mb + (size_t)r_t * C + c_t] = l;
                } else if (MODE == 1) {
                    float w = ((r_t == c_t) ? 1.5f : 0.f) - 0.5f * v;
                    short h, l;
                    bfsplit(w, h, l);
                    o0[mb + (size_t)r_t * C + c_t] = h;
                    o0[(size_t)PL + mb + (size_t)r_t * C + c_t] = l;
                } else if (MODE == 3) {
                    float a = v * invT;
                    short h, l;
                    bfsplit(a, h, l);
                    o0[mb + (size_t)r_t * C + c_t] = h;
                    o0[(size_t)PL + mb + (size_t)r_t * C + c_t] = l;
                    float w = ((r_t == c_t) ? 1.5f : 0.f) - 0.5f * a;
                    bfsplit(w, h, l);
                    o1[mb + (size_t)r_t * C + c_t] = h;
                    o1[(size_t)PL + mb + (size_t)r_t * C + c_t] = l;
                } else {
                    if (c_t >= r_t) {
                        int off = r_t * C - (r_t * (r_t - 1)) / 2 - r_t + c_t;
                        outf[(size_t)b * OUTPB + off] = v * scale;
                    }
                }
            }
        }
    }
}

// ---------------------------------------------------------------------------
extern "C" void kernel_launch(void* const* d_in, const int* in_sizes, int n_in,
                              void* d_out, int out_size, void* d_ws, size_t ws_size,
                              hipStream_t stream) {
    const float* x = (const float*)d_in[0];
    float* out = (float*)d_out;
    short* base = (short*)d_ws;
    short* buf0 = base;
    short* buf1 = base + (size_t)2 * PL;
    short* buf2 = base + (size_t)4 * PL;
    short* buf3 = base + (size_t)6 * PL;
    float* trsum = (float*)(base + (size_t)8 * PL);
    float* rowsq = trsum + 256;

    dim3 blk(256);
    dim3 g(2, 4, BATCH);

    // xc (centered, split, padded) -> buf2 ; rowsq[row] = sum(xc_row^2)
    convert_k<<<dim3(BATCH * C / 4), blk, 0, stream>>>(x, buf2, rowsq);
    tracered_k<<<dim3(BATCH), blk, 0, stream>>>(rowsq, trsum);
    // Gram + prep: A -> buf0, B1 -> buf1
    mm_k<3><<<g, blk, 0, stream>>>(buf2, buf2, buf0, buf1, nullptr, trsum);
    // Y1 = A @ B1 -> buf2 ; Z = B1 (buf1)
    mm_k<0><<<g, blk, 0, stream>>>(buf0, buf1, buf2, nullptr, nullptr, nullptr);
    // iter 1: Z=1 Y=2 -> Bn=3, Ynew=0, Znew=2
    mm_k<1><<<g, blk, 0, stream>>>(buf1, buf2, buf3, nullptr, nullptr, nullptr);
    mm_k<0><<<g, blk, 0, stream>>>(buf2, buf3, buf0, nullptr, nullptr, nullptr);
    mm_k<0><<<g, blk, 0, stream>>>(buf3, buf1, buf2, nullptr, nullptr, nullptr);
    // iter 2: Z=2 Y=0 -> Bn=1, Ynew=3, Znew=0
    mm_k<1><<<g, blk, 0, stream>>>(buf2, buf0, buf1, nullptr, nullptr, nullptr);
    mm_k<0><<<g, blk, 0, stream>>>(buf0, buf1, buf3, nullptr, nullptr, nullptr);
    mm_k<0><<<g, blk, 0, stream>>>(buf1, buf2, buf0, nullptr, nullptr, nullptr);
    // iter 3: Z=0 Y=3 -> Bn=1, Ynew=2, Znew=3
    mm_k<1><<<g, blk, 0, stream>>>(buf0, buf3, buf1, nullptr, nullptr, nullptr);
    mm_k<0><<<g, blk, 0, stream>>>(buf3, buf1, buf2, nullptr, nullptr, nullptr);
    mm_k<0><<<g, blk, 0, stream>>>(buf1, buf0, buf3, nullptr, nullptr, nullptr);
    // final: Z=3 Y=2 -> Bf=0 ; out = triu(Y @ Bf * sqrt(tr))
    mm_k<1><<<g, blk, 0, stream>>>(buf3, buf2, buf0, nullptr, nullptr, nullptr);
    mm_k<2><<<g, blk, 0, stream>>>(buf2, buf0, nullptr, nullptr, out, trsum);
}

// Round 4
// 220.589 us; speedup vs baseline: 2.7514x; 1.4178x over previous
//
#include <hip/hip_runtime.h>
#include <math.h>

#define C      256
#define NPIX   196
#define BATCH  64
#define MAT    65536                  // C*C
#define PL     4194304                // BATCH*MAT  (one bf16 plane, in elements)
#define OUTPB  32896                  // C*(C+1)/2

typedef short s16x8 __attribute__((ext_vector_type(8)));
typedef float f32x4 __attribute__((ext_vector_type(4)));

// ---- bf16 split helpers (RNE) ---------------------------------------------
__device__ __forceinline__ short bfhi(float v) {
    unsigned int u = __float_as_uint(v);
    u = (u + 0x7fffu + ((u >> 16) & 1u)) >> 16;
    return (short)u;
}
__device__ __forceinline__ float bff(short h) {
    return __uint_as_float(((unsigned int)(unsigned short)h) << 16);
}
__device__ __forceinline__ void bfsplit(float v, short& h, short& l) {
    h = bfhi(v);
    l = bfhi(v - bff(h));
}

// ---------------------------------------------------------------------------
// convert: row-mean centering, bf16 hi/lo split, zero-pad K 196->256.
// XCD-pinned: batch b handled by XCD b%8 (bid%8 == XCD round-robin heuristic).
// ---------------------------------------------------------------------------
__global__ __launch_bounds__(256) void convert_k(const float* __restrict__ x,
                                                 short* __restrict__ xc,
                                                 float* __restrict__ rowsq) {
    const int bid = blockIdx.x;               // 4096 blocks
    const int xcd = bid & 7, j = bid >> 3;    // j in [0,512)
    const int lb = j & 7, rc = j >> 3;        // rc in [0,64)
    const int b = xcd + (lb << 3);
    const int wave = threadIdx.x >> 6, lane = threadIdx.x & 63;
    const int row = rc * 4 + wave;            // [0,256)
    const int rowg = b * 256 + row;
    const float* xr = x + (size_t)rowg * NPIX;
    float v[4];
    #pragma unroll
    for (int i = 0; i < 4; ++i) {
        int c = lane + (i << 6);
        v[i] = (c < NPIX) ? xr[c] : 0.f;
    }
    float s = v[0] + v[1] + v[2] + v[3];
    #pragma unroll
    for (int off = 32; off; off >>= 1) s += __shfl_xor(s, off, 64);
    const float mean = s * (1.f / NPIX);

    short* oh = xc + (size_t)b * MAT + (size_t)row * C;
    short* ol = oh + PL;
    float sq = 0.f;
    #pragma unroll
    for (int i = 0; i < 4; ++i) {
        int c = lane + (i << 6);
        float w = (c < NPIX) ? (v[i] - mean) : 0.f;
        sq += w * w;
        short h, l;
        bfsplit(w, h, l);
        oh[c] = h;
        ol[c] = l;
    }
    #pragma unroll
    for (int off = 32; off; off >>= 1) sq += __shfl_xor(sq, off, 64);
    if (lane == 0) rowsq[rowg] = sq;
}

// ---------------------------------------------------------------------------
// trsum[b] = sum_c rowsq[b*256+c]   (64 blocks; bid==b keeps XCD pinning)
// ---------------------------------------------------------------------------
__global__ __launch_bounds__(256) void tracered_k(const float* __restrict__ rowsq,
                                                  float* __restrict__ trsum) {
    const int b = blockIdx.x, t = threadIdx.x;
    float v = rowsq[b * 256 + t];
    __shared__ float red[4];
    #pragma unroll
    for (int off = 32; off; off >>= 1) v += __shfl_xor(v, off, 64);
    if ((t & 63) == 0) red[t >> 6] = v;
    __syncthreads();
    if (t == 0) trsum[b] = red[0] + red[1] + red[2] + red[3];
}

// ---------------------------------------------------------------------------
// Batched 256x256x256 split-bf16 MFMA matmul, tile BM=64 x BN=128.
// Flat 1-D grid, XCD-pinned decode: bid -> (xcd, tile, local-batch, half),
// batch = xcd + 8*lb so batch b is ALWAYS on XCD b%8 in every launch ->
// the whole NS chain for b stays in that XCD's L2.
// MODE 0: o0 = A@B        MODE 1: o0 = 1.5I - 0.5 A@B
// MODE 2: outf = triu_packed(A@B * sqrt(tr/n))
// MODE 3: (gram) o0 = P/trsum ; o1 = 1.5I - 0.5*o0
// MODE 4: pair — half 0: o0 = A0@B ; half 1: o1 = A1@B  (grid 2x)
// ---------------------------------------------------------------------------
template <int MODE>
__global__ __launch_bounds__(256) void mm_k(const short* __restrict__ A0,
                                            const short* __restrict__ A1,
                                            const short* __restrict__ Bop,
                                            short* __restrict__ o0,
                                            short* __restrict__ o1,
                                            float* __restrict__ outf,
                                            const float* __restrict__ trsum) {
    const int bid = blockIdx.x;
    const int xcd = bid & 7, j = bid >> 3;
    const int t8 = j & 7;
    const int bm = t8 >> 1, bn = t8 & 1;
    const int q = j >> 3;
    const int b = xcd + ((q & 7) << 3);
    const int half = (MODE == 4) ? (q >> 3) : 0;
    if (MODE == 2 && bn == 0 && bm >= 2) return;   // fully strictly-lower tile

    __shared__ __align__(16) short lds[24576];     // Ah,Al: 2x4096  Bh,Bl: 2x8192

    const int t = threadIdx.x;
    const int lane = t & 63, wid = t >> 6;
    const int wr = wid >> 1, wc = wid & 1;         // wave grid 2x2
    const int lr = lane & 15, lg = lane >> 4;

    const size_t mb = (size_t)b * MAT;
    const short* Ap = ((MODE == 4 && half) ? A1 : A0) + mb;
    const short* Bp = Bop + mb;
    const int rowA0 = bm * 64, rowB0 = bn * 128;

    f32x4 acc[2][4];
    const f32x4 zero = {0.f, 0.f, 0.f, 0.f};
    #pragma unroll
    for (int i = 0; i < 2; ++i)
        #pragma unroll
        for (int jj = 0; jj < 4; ++jj) acc[i][jj] = zero;

    for (int k0 = 0; k0 < C; k0 += 64) {
        #pragma unroll
        for (int i = 0; i < 12; ++i) {
            const int u = i * 256 + t;
            int plane, rr, ch, ldsbase;
            const short* src;
            if (i < 4) {
                plane = u >> 9; rr = (u >> 3) & 63; ch = u & 7;
                src = Ap + (size_t)plane * PL + (size_t)(rowA0 + rr) * C;
                ldsbase = plane * 4096;
            } else {
                const int v2 = u - 1024;
                plane = v2 >> 10; rr = (v2 >> 3) & 127; ch = v2 & 7;
                src = Bp + (size_t)plane * PL + (size_t)(rowB0 + rr) * C;
                ldsbase = 8192 + plane * 8192;
            }
            s16x8 v = *(const s16x8*)(src + k0 + ch * 8);
            *(s16x8*)&lds[ldsbase + rr * 64 + ((ch ^ (rr & 7)) << 3)] = v;
        }
        __syncthreads();
        #pragma unroll
        for (int kk = 0; kk < 64; kk += 32) {
            s16x8 ah[2], al[2], bh[4], bl[4];
            #pragma unroll
            for (int i = 0; i < 2; ++i) {
                const int ra = wr * 32 + i * 16 + lr;
                const int ca = ((kk >> 3) + lg) ^ (ra & 7);
                ah[i] = *(const s16x8*)&lds[ra * 64 + (ca << 3)];
                al[i] = *(const s16x8*)&lds[4096 + ra * 64 + (ca << 3)];
            }
            #pragma unroll
            for (int jj = 0; jj < 4; ++jj) {
                const int rb = wc * 64 + jj * 16 + lr;
                const int cb = ((kk >> 3) + lg) ^ (rb & 7);
                bh[jj] = *(const s16x8*)&lds[8192 + rb * 64 + (cb << 3)];
                bl[jj] = *(const s16x8*)&lds[16384 + rb * 64 + (cb << 3)];
            }
            #pragma unroll
            for (int i = 0; i < 2; ++i)
                #pragma unroll
                for (int jj = 0; jj < 4; ++jj) {
                    acc[i][jj] = __builtin_amdgcn_mfma_f32_16x16x32_bf16(ah[i], bh[jj], acc[i][jj], 0, 0, 0);
                    acc[i][jj] = __builtin_amdgcn_mfma_f32_16x16x32_bf16(ah[i], bl[jj], acc[i][jj], 0, 0, 0);
                    acc[i][jj] = __builtin_amdgcn_mfma_f32_16x16x32_bf16(al[i], bh[jj], acc[i][jj], 0, 0, 0);
                }
        }
        __syncthreads();
    }

    // ---- epilogue ----
    float ts = 0.f;
    if (MODE == 2 || MODE == 3) ts = trsum[b];
    const float invT  = (MODE == 3) ? (1.f / ts) : 0.f;
    const float scale = (MODE == 2) ? sqrtf(ts * (1.f / NPIX)) : 0.f;
    short* dst = (MODE == 4 && half) ? o1 : o0;

    #pragma unroll
    for (int i = 0; i < 2; ++i) {
        #pragma unroll
        for (int jj = 0; jj < 4; ++jj) {
            #pragma unroll
            for (int qq = 0; qq < 4; ++qq) {
                const int r_t = bm * 64 + wr * 32 + i * 16 + lg * 4 + qq;
                const int c_t = bn * 128 + wc * 64 + jj * 16 + lr;
                const float v = acc[i][jj][qq];
                if (MODE == 0 || MODE == 4) {
                    short h, l;
                    bfsplit(v, h, l);
                    dst[mb + (size_t)r_t * C + c_t] = h;
                    dst[(size_t)PL + mb + (size_t)r_t * C + c_t] = l;
                } else if (MODE == 1) {
                    float w = ((r_t == c_t) ? 1.5f : 0.f) - 0.5f * v;
                    short h, l;
                    bfsplit(w, h, l);
                    o0[mb + (size_t)r_t * C + c_t] = h;
                    o0[(size_t)PL + mb + (size_t)r_t * C + c_t] = l;
                } else if (MODE == 3) {
                    float a = v * invT;
                    short h, l;
                    bfsplit(a, h, l);
                    o0[mb + (size_t)r_t * C + c_t] = h;
                    o0[(size_t)PL + mb + (size_t)r_t * C + c_t] = l;
                    float w = ((r_t == c_t) ? 1.5f : 0.f) - 0.5f * a;
                    bfsplit(w, h, l);
                    o1[mb + (size_t)r_t * C + c_t] = h;
                    o1[(size_t)PL + mb + (size_t)r_t * C + c_t] = l;
                } else if (MODE == 2) {
                    if (c_t >= r_t) {
                        int off = r_t * C - (r_t * (r_t - 1)) / 2 - r_t + c_t;
                        outf[(size_t)b * OUTPB + off] = v * scale;
                    }
                }
            }
        }
    }
}

// ---------------------------------------------------------------------------
extern "C" void kernel_launch(void* const* d_in, const int* in_sizes, int n_in,
                              void* d_out, int out_size, void* d_ws, size_t ws_size,
                              hipStream_t stream) {
    const float* x = (const float*)d_in[0];
    float* out = (float*)d_out;
    short* base = (short*)d_ws;
    short* b0 = base;
    short* b1 = base + (size_t)2 * PL;
    short* b2 = base + (size_t)4 * PL;
    short* b3 = base + (size_t)6 * PL;
    short* b4 = base + (size_t)8 * PL;   // doubles as xc
    float* trsum = (float*)(base + (size_t)10 * PL);
    float* rowsq = trsum + 256;

    dim3 blk(256);

    // xc (centered, split, padded) -> b4 ; rowsq
    convert_k<<<dim3(4096), blk, 0, stream>>>(x, b4, rowsq);
    tracered_k<<<dim3(64), blk, 0, stream>>>(rowsq, trsum);
    // gram: A -> b0, Z1 -> b1
    mm_k<3><<<dim3(512), blk, 0, stream>>>(b4, b4, b4, b0, b1, nullptr, trsum);
    // Y1 = A @ Z1 -> b2            (Y=b2, Z=b1)
    mm_k<0><<<dim3(512), blk, 0, stream>>>(b0, b0, b1, b2, nullptr, nullptr, nullptr);
    // iter 1
    mm_k<1><<<dim3(512), blk, 0, stream>>>(b1, b1, b2, b3, nullptr, nullptr, nullptr);   // Bn1=b3
    mm_k<4><<<dim3(1024), blk, 0, stream>>>(b2, b1, b3, b0, b4, nullptr, nullptr);       // Y->b0, Z->b4
    // iter 2
    mm_k<1><<<dim3(512), blk, 0, stream>>>(b4, b4, b0, b1, nullptr, nullptr, nullptr);   // Bn2=b1
    mm_k<4><<<dim3(1024), blk, 0, stream>>>(b0, b4, b1, b2, b3, nullptr, nullptr);       // Y->b2, Z->b3
    // iter 3
    mm_k<1><<<dim3(512), blk, 0, stream>>>(b3, b3, b2, b0, nullptr, nullptr, nullptr);   // Bn3=b0
    mm_k<4><<<dim3(1024), blk, 0, stream>>>(b2, b3, b0, b4, b1, nullptr, nullptr);       // Y->b4, Z->b1
    // final
    mm_k<1><<<dim3(512), blk, 0, stream>>>(b1, b1, b4, b2, nullptr, nullptr, nullptr);   // Bf=b2
    mm_k<2><<<dim3(512), blk, 0, stream>>>(b4, b4, b2, nullptr, nullptr, out, trsum);    // out
}